// Round 1
// baseline (11889.111 us; speedup 1.0000x reference)
//
#include <hip/hip_runtime.h>

// MatchLSTM forward, fp32 baseline (Round 0).
//
// Structure:
//   Phase A (parallel):
//     h_s  = gates(embed[premise]  @ Wih_p.T + b)        [64,128,512]
//     h_t  = gates(embed[hypothesis]@ Wih_h.T + b)       [64,128,512]
//     pre_s = h_s @ Ws.T                                  [64,128,512]
//     pre_t = h_t @ Wt.T                                  [64,128,512]
//     pre_m_h[k,b,(i,g,o),j] = h_t-half of match-cell preactivation (+biases)
//   Phase B (sequential, 64 steps; dependency only through h_m):
//     wm   = h_m @ Wm.T                                   [128,512]
//     attn: scores->softmax(t)->a_k (1 WG per batch elem) [128,512]
//     h_m  = gates(a @ Wih_m[:, :512].T + pre_m_h[k])     [128,512]
//   out = h_m @ fc_w.T + fc_b                             [128,3]
//
// Gate order i,f,g,o; f unused (zero initial cell state) -> 3 dots per output.

#define DEV static __device__ __forceinline__

DEV float fast_sigmoid(float x) { return 1.0f / (1.0f + __expf(-x)); }
DEV float fast_tanh(float x)    { return 1.0f - 2.0f / (__expf(2.0f * x) + 1.0f); }

// ---------------------------------------------------------------------------
// gemm3: C-tiles of out[m, j] built from NG dot products against W rows
// {j, 1024+j, 1536+j} (gate rows i, g, o) or just {j} for NG=1.
// A is [M, lda] (optionally gathered through gidx into embed rows).
// W is [rows, ldw], row-major, dot over k (both operands K-contiguous).
// MODE: 0 = encoder (add biases, apply LSTM gates -> h)
//       1 = store 3 raw preactivations (+biases) to out[(m*3+g)*512+j]
//       2 = match step: add add3[(m*3+g)*512+j], apply gates -> h
//       3 = plain single-dot store out[m*512+j]
// Tiles: BM x 32 output block, BK=32, 256 threads, thread = (TM x 2 x NG) accs.
// ---------------------------------------------------------------------------
template<int BM, int NG, int MODE, int GATHER>
__global__ __launch_bounds__(256) void gemm3_kernel(
    const float* __restrict__ A, const int* __restrict__ gidx, int lda,
    const float* __restrict__ W, int ldw, int K,
    const float* __restrict__ bias1, const float* __restrict__ bias2,
    const float* __restrict__ add3, float* __restrict__ out)
{
    constexpr int BK = 32;
    constexpr int TM = BM / 16;          // 4 (BM=64) or 2 (BM=32)
    constexpr int TJ = 2;
    constexpr int AP = BM + 4;           // row stride pad: keeps 16B alignment
    constexpr int WP = NG * 32 + 4;
    __shared__ __align__(16) float As[BK][AP];    // k-major A tile
    __shared__ __align__(16) float Wsh[BK][WP];   // k-major W tile (NG*32 rows)

    const int tid = threadIdx.x;
    const int ty = tid >> 4;             // m group (16)
    const int tx = tid & 15;             // j group (16)
    const int m0 = blockIdx.x * BM;
    const int j0 = blockIdx.y * 32;

    float acc[TM][TJ][NG];
#pragma unroll
    for (int im = 0; im < TM; ++im)
#pragma unroll
        for (int ij = 0; ij < TJ; ++ij)
#pragma unroll
            for (int g = 0; g < NG; ++g) acc[im][ij][g] = 0.0f;

    for (int k0 = 0; k0 < K; k0 += BK) {
        // stage A tile (transposed to k-major)
#pragma unroll
        for (int i = tid; i < BM * BK; i += 256) {
            int r = i >> 5, c = i & 31;
            int gk = k0 + c;
            float v = 0.0f;
            if (gk < K) {
                int arow = GATHER ? gidx[m0 + r] : (m0 + r);
                v = A[arow * lda + gk];
            }
            As[c][r] = v;
        }
        // stage W tile: rows ROFF[g] + j0 + jj
#pragma unroll
        for (int i = tid; i < NG * 32 * BK; i += 256) {
            int rl = i >> 5, c = i & 31;
            int g = rl >> 5, jj = rl & 31;
            int row = (g == 0 ? 0 : (g == 1 ? 1024 : 1536)) + j0 + jj;
            int gk = k0 + c;
            float v = (gk < K) ? W[row * ldw + gk] : 0.0f;
            Wsh[c][rl] = v;
        }
        __syncthreads();
#pragma unroll
        for (int kk = 0; kk < BK; ++kk) {
            float av[TM];
            if constexpr (TM == 4) {
                float4 t4 = *reinterpret_cast<const float4*>(&As[kk][ty * 4]);
                av[0] = t4.x; av[1] = t4.y; av[2] = t4.z; av[3] = t4.w;
            } else {
                float2 t2 = *reinterpret_cast<const float2*>(&As[kk][ty * 2]);
                av[0] = t2.x; av[1] = t2.y;
            }
#pragma unroll
            for (int g = 0; g < NG; ++g) {
                float2 w2 = *reinterpret_cast<const float2*>(&Wsh[kk][g * 32 + tx * 2]);
#pragma unroll
                for (int im = 0; im < TM; ++im) {
                    acc[im][0][g] += av[im] * w2.x;
                    acc[im][1][g] += av[im] * w2.y;
                }
            }
        }
        __syncthreads();
    }

#pragma unroll
    for (int im = 0; im < TM; ++im) {
        int m = m0 + ty * TM + im;
#pragma unroll
        for (int ij = 0; ij < TJ; ++ij) {
            int j = j0 + tx * TJ + ij;
            if constexpr (MODE == 3) {
                out[m * 512 + j] = acc[im][ij][0];
            } else if constexpr (MODE == 1) {
                out[(m * 3 + 0) * 512 + j] = acc[im][ij][0] + bias1[j] + bias2[j];
                out[(m * 3 + 1) * 512 + j] = acc[im][ij][1] + bias1[1024 + j] + bias2[1024 + j];
                out[(m * 3 + 2) * 512 + j] = acc[im][ij][2] + bias1[1536 + j] + bias2[1536 + j];
            } else if constexpr (MODE == 0) {
                float gi = acc[im][ij][0] + bias1[j] + bias2[j];
                float gg = acc[im][ij][1] + bias1[1024 + j] + bias2[1024 + j];
                float go = acc[im][ij][2] + bias1[1536 + j] + bias2[1536 + j];
                float c  = fast_sigmoid(gi) * fast_tanh(gg);
                out[m * 512 + j] = fast_sigmoid(go) * fast_tanh(c);
            } else { // MODE == 2
                float gi = acc[im][ij][0] + add3[(m * 3 + 0) * 512 + j];
                float gg = acc[im][ij][1] + add3[(m * 3 + 1) * 512 + j];
                float go = acc[im][ij][2] + add3[(m * 3 + 2) * 512 + j];
                float c  = fast_sigmoid(gi) * fast_tanh(gg);
                out[m * 512 + j] = fast_sigmoid(go) * fast_tanh(c);
            }
        }
    }
}

// ---------------------------------------------------------------------------
// Attention for step k: one workgroup per batch element b.
// scores[t] = sum_h w_e[h] * tanh(pre_s[t,b,h] + pre_t[k,b,h] + wm[b,h])
// alpha = softmax_t(scores); a[b,h] = sum_t alpha[t] * h_s[t,b,h]
// ---------------------------------------------------------------------------
__global__ __launch_bounds__(256) void attn_kernel(
    const float* __restrict__ pre_s, const float* __restrict__ pre_t,
    const float* __restrict__ wm, const float* __restrict__ w_e,
    const float* __restrict__ h_s, float* __restrict__ a_out, int k)
{
    const int b = blockIdx.x;
    const int tid = threadIdx.x;
    __shared__ float base[512];
    __shared__ float wsh[512];
    __shared__ float sc[64];

#pragma unroll
    for (int r = 0; r < 2; ++r) {
        int h = tid + r * 256;
        base[h] = pre_t[(k * 128 + b) * 512 + h] + wm[b * 512 + h];
        wsh[h] = w_e[h];
    }
    __syncthreads();

    const int wv = tid >> 6, lane = tid & 63;
    for (int tt = 0; tt < 16; ++tt) {           // 4 waves x 16 t each
        int t = wv * 16 + tt;
        const float* ps = pre_s + (t * 128 + b) * 512;
        float p = 0.0f;
#pragma unroll
        for (int u = 0; u < 8; ++u) {
            int h = lane + 64 * u;
            p += wsh[h] * fast_tanh(ps[h] + base[h]);
        }
#pragma unroll
        for (int off = 32; off; off >>= 1) p += __shfl_xor(p, off);
        if (lane == 0) sc[t] = p;
    }
    __syncthreads();
    if (wv == 0) {                               // softmax over 64 t's, one wave
        float s = sc[lane];
        float mx = s;
#pragma unroll
        for (int off = 32; off; off >>= 1) mx = fmaxf(mx, __shfl_xor(mx, off));
        float e = __expf(s - mx);
        float sum = e;
#pragma unroll
        for (int off = 32; off; off >>= 1) sum += __shfl_xor(sum, off);
        sc[lane] = e / sum;
    }
    __syncthreads();
#pragma unroll
    for (int r = 0; r < 2; ++r) {
        int h = tid + r * 256;
        float acc = 0.0f;
        for (int t = 0; t < 64; ++t)
            acc += sc[t] * h_s[(t * 128 + b) * 512 + h];
        a_out[b * 512 + h] = acc;
    }
}

// out[b,c] = h_m[b,:] . fc_w[c,:] + fc_b[c]; one wave per output.
__global__ __launch_bounds__(256) void fc_kernel(
    const float* __restrict__ h_m, const float* __restrict__ fc_w,
    const float* __restrict__ fc_b, float* __restrict__ out)
{
    const int wv = threadIdx.x >> 6, lane = threadIdx.x & 63;
    const int idx = blockIdx.x * 4 + wv;         // 0..383
    if (idx >= 384) return;
    const int b = idx / 3, c = idx % 3;
    float p = 0.0f;
#pragma unroll
    for (int u = 0; u < 8; ++u) {
        int h = lane + 64 * u;
        p += h_m[b * 512 + h] * fc_w[c * 512 + h];
    }
#pragma unroll
    for (int off = 32; off; off >>= 1) p += __shfl_xor(p, off);
    if (lane == 0) out[b * 3 + c] = p + fc_b[c];
}

__global__ void zero_kernel(float* __restrict__ p, int n)
{
    int i = blockIdx.x * 256 + threadIdx.x;
    if (i < n) p[i] = 0.0f;
}

extern "C" void kernel_launch(void* const* d_in, const int* in_sizes, int n_in,
                              void* d_out, int out_size, void* d_ws, size_t ws_size,
                              hipStream_t stream)
{
    (void)in_sizes; (void)n_in; (void)out_size;
    const int*   premise    = (const int*)d_in[0];
    // d_in[1] premise_len: unused by reference
    const int*   hypothesis = (const int*)d_in[2];
    // d_in[3] hypothesis_len: unused by reference
    const float* embed  = (const float*)d_in[4];
    const float* w_e    = (const float*)d_in[5];
    const float* Ws     = (const float*)d_in[6];
    const float* Wt     = (const float*)d_in[7];
    const float* Wm     = (const float*)d_in[8];
    const float* Wih_p  = (const float*)d_in[9];
    const float* bih_p  = (const float*)d_in[10];
    const float* bhh_p  = (const float*)d_in[11];
    const float* Wih_h  = (const float*)d_in[12];
    const float* bih_h  = (const float*)d_in[13];
    const float* bhh_h  = (const float*)d_in[14];
    const float* Wih_m  = (const float*)d_in[15];
    const float* bih_m  = (const float*)d_in[16];
    const float* bhh_m  = (const float*)d_in[17];
    const float* fc_w   = (const float*)d_in[18];
    const float* fc_b   = (const float*)d_in[19];

    // workspace layout (floats)
    float* ws      = (float*)d_ws;
    float* h_s     = ws;                      // 8192*512
    float* h_t     = h_s    + 4194304;        // 8192*512
    float* pre_s   = h_t    + 4194304;        // 8192*512
    float* pre_t   = pre_s  + 4194304;        // 8192*512
    float* pre_m_h = pre_t  + 4194304;        // 8192*3*512
    float* h_m     = pre_m_h + 12582912;      // 128*512
    float* wm      = h_m    + 65536;          // 128*512
    float* a_buf   = wm     + 65536;          // 128*512
    if (ws_size < (size_t)29556736 * 4) return;  // ~113 MiB required

    dim3 blk(256);

    zero_kernel<<<256, blk, 0, stream>>>(h_m, 65536);

    // Phase A
    gemm3_kernel<64, 3, 0, 1><<<dim3(128, 16), blk, 0, stream>>>(
        embed, premise, 300, Wih_p, 300, 300, bih_p, bhh_p, nullptr, h_s);
    gemm3_kernel<64, 3, 0, 1><<<dim3(128, 16), blk, 0, stream>>>(
        embed, hypothesis, 300, Wih_h, 300, 300, bih_h, bhh_h, nullptr, h_t);
    gemm3_kernel<64, 1, 3, 0><<<dim3(128, 16), blk, 0, stream>>>(
        h_s, nullptr, 512, Ws, 512, 512, nullptr, nullptr, nullptr, pre_s);
    gemm3_kernel<64, 1, 3, 0><<<dim3(128, 16), blk, 0, stream>>>(
        h_t, nullptr, 512, Wt, 512, 512, nullptr, nullptr, nullptr, pre_t);
    // hypothesis half of match-cell preactivation (cols 512..1023 of Wih_m)
    gemm3_kernel<64, 3, 1, 0><<<dim3(128, 16), blk, 0, stream>>>(
        h_t, nullptr, 512, Wih_m + 512, 1024, 512, bih_m, bhh_m, nullptr, pre_m_h);

    // Phase B: 64 sequential match-LSTM steps
    for (int k = 0; k < 64; ++k) {
        gemm3_kernel<32, 1, 3, 0><<<dim3(4, 16), blk, 0, stream>>>(
            h_m, nullptr, 512, Wm, 512, 512, nullptr, nullptr, nullptr, wm);
        attn_kernel<<<128, blk, 0, stream>>>(pre_s, pre_t, wm, w_e, h_s, a_buf, k);
        gemm3_kernel<32, 3, 2, 0><<<dim3(4, 16), blk, 0, stream>>>(
            a_buf, nullptr, 512, Wih_m, 1024, 512, nullptr, nullptr,
            pre_m_h + (size_t)k * 196608, h_m);
    }

    fc_kernel<<<96, blk, 0, stream>>>(h_m, fc_w, fc_b, (float*)d_out);
}

// Round 3
// 7915.076 us; speedup vs baseline: 1.5021x; 1.5021x over previous
//
#include <hip/hip_runtime.h>

// MatchLSTM forward (Round 3): phase A = 5 fp32 tiled GEMM dispatches,
// phase B = ONE persistent plain-launch kernel (64 steps) with a hand-rolled
// grid barrier (device-scope atomics) — hipLaunchCooperativeKernel silently
// failed under this harness in Round 2 (d_out never written).

#define DEV static __device__ __forceinline__

DEV float fast_sigmoid(float x) { return 1.0f / (1.0f + __expf(-x)); }
DEV float fast_tanh(float x)    { return 1.0f - 2.0f / (__expf(2.0f * x) + 1.0f); }

// Grid-wide barrier: monotonically increasing counter, no reset needed.
// Release/acquire via __threadfence (agent scope → L2 writeback/invalidate
// for cross-XCD visibility). Grid (128 blocks) <= 256 CUs → all co-resident.
DEV void gsync(int* bar, int target)
{
    __syncthreads();
    if (threadIdx.x == 0) {
        __threadfence();                       // release: drain + make visible
        __hip_atomic_fetch_add(bar, 1, __ATOMIC_ACQ_REL, __HIP_MEMORY_SCOPE_AGENT);
        while (__hip_atomic_load(bar, __ATOMIC_ACQUIRE, __HIP_MEMORY_SCOPE_AGENT) < target)
            __builtin_amdgcn_s_sleep(4);
        __threadfence();                       // acquire: invalidate stale lines
    }
    __syncthreads();
}

// ---------------------------------------------------------------------------
// Phase A GEMM (unchanged from Round 1; verified passing).
// ---------------------------------------------------------------------------
template<int BM, int NG, int MODE, int GATHER>
__global__ __launch_bounds__(256) void gemm3_kernel(
    const float* __restrict__ A, const int* __restrict__ gidx, int lda,
    const float* __restrict__ W, int ldw, int K,
    const float* __restrict__ bias1, const float* __restrict__ bias2,
    const float* __restrict__ add3, float* __restrict__ out)
{
    constexpr int BK = 32;
    constexpr int TM = BM / 16;
    constexpr int TJ = 2;
    constexpr int AP = BM + 4;
    constexpr int WP = NG * 32 + 4;
    __shared__ __align__(16) float As[BK][AP];
    __shared__ __align__(16) float Wsh[BK][WP];

    const int tid = threadIdx.x;
    const int ty = tid >> 4;
    const int tx = tid & 15;
    const int m0 = blockIdx.x * BM;
    const int j0 = blockIdx.y * 32;

    float acc[TM][TJ][NG];
#pragma unroll
    for (int im = 0; im < TM; ++im)
#pragma unroll
        for (int ij = 0; ij < TJ; ++ij)
#pragma unroll
            for (int g = 0; g < NG; ++g) acc[im][ij][g] = 0.0f;

    for (int k0 = 0; k0 < K; k0 += BK) {
#pragma unroll
        for (int i = tid; i < BM * BK; i += 256) {
            int r = i >> 5, c = i & 31;
            int gk = k0 + c;
            float v = 0.0f;
            if (gk < K) {
                int arow = GATHER ? gidx[m0 + r] : (m0 + r);
                v = A[arow * lda + gk];
            }
            As[c][r] = v;
        }
#pragma unroll
        for (int i = tid; i < NG * 32 * BK; i += 256) {
            int rl = i >> 5, c = i & 31;
            int g = rl >> 5, jj = rl & 31;
            int row = (g == 0 ? 0 : (g == 1 ? 1024 : 1536)) + j0 + jj;
            int gk = k0 + c;
            float v = (gk < K) ? W[row * ldw + gk] : 0.0f;
            Wsh[c][rl] = v;
        }
        __syncthreads();
#pragma unroll
        for (int kk = 0; kk < BK; ++kk) {
            float av[TM];
            if constexpr (TM == 4) {
                float4 t4 = *reinterpret_cast<const float4*>(&As[kk][ty * 4]);
                av[0] = t4.x; av[1] = t4.y; av[2] = t4.z; av[3] = t4.w;
            } else {
                float2 t2 = *reinterpret_cast<const float2*>(&As[kk][ty * 2]);
                av[0] = t2.x; av[1] = t2.y;
            }
#pragma unroll
            for (int g = 0; g < NG; ++g) {
                float2 w2 = *reinterpret_cast<const float2*>(&Wsh[kk][g * 32 + tx * 2]);
#pragma unroll
                for (int im = 0; im < TM; ++im) {
                    acc[im][0][g] += av[im] * w2.x;
                    acc[im][1][g] += av[im] * w2.y;
                }
            }
        }
        __syncthreads();
    }

#pragma unroll
    for (int im = 0; im < TM; ++im) {
        int m = m0 + ty * TM + im;
#pragma unroll
        for (int ij = 0; ij < TJ; ++ij) {
            int j = j0 + tx * TJ + ij;
            if constexpr (MODE == 3) {
                out[m * 512 + j] = acc[im][ij][0];
            } else if constexpr (MODE == 1) {
                out[(m * 3 + 0) * 512 + j] = acc[im][ij][0] + bias1[j] + bias2[j];
                out[(m * 3 + 1) * 512 + j] = acc[im][ij][1] + bias1[1024 + j] + bias2[1024 + j];
                out[(m * 3 + 2) * 512 + j] = acc[im][ij][2] + bias1[1536 + j] + bias2[1536 + j];
            } else if constexpr (MODE == 0) {
                float gi = acc[im][ij][0] + bias1[j] + bias2[j];
                float gg = acc[im][ij][1] + bias1[1024 + j] + bias2[1024 + j];
                float go = acc[im][ij][2] + bias1[1536 + j] + bias2[1536 + j];
                float c  = fast_sigmoid(gi) * fast_tanh(gg);
                out[m * 512 + j] = fast_sigmoid(go) * fast_tanh(c);
            } else {
                float gi = acc[im][ij][0] + add3[(m * 3 + 0) * 512 + j];
                float gg = acc[im][ij][1] + add3[(m * 3 + 1) * 512 + j];
                float go = acc[im][ij][2] + add3[(m * 3 + 2) * 512 + j];
                float c  = fast_sigmoid(gi) * fast_tanh(gg);
                out[m * 512 + j] = fast_sigmoid(go) * fast_tanh(c);
            }
        }
    }
}

// ---------------------------------------------------------------------------
// Phase B: persistent kernel, plain launch, 128 WGs x 256 threads.
// Per step k:
//   P1 (k>0): wm[b,j] = sum_h h_m[b,h] * Wm[j,h]      WG = (b-half, 8-j slice)
//   P2:       scores -> softmax(t) -> a[b,:]           WG = b
//   P3:       h_m[b,j] = gates(a . Wih_m[:, :512] + pre_m_h[k])  same tiling
// 3 grid barriers per step. FC epilogue inline after step 63.
// ---------------------------------------------------------------------------
__global__ __launch_bounds__(256) void phaseB_kernel(
    const float* __restrict__ pre_s, const float* __restrict__ pre_t,
    const float* __restrict__ h_s,   const float* __restrict__ pre_m_h,
    const float* __restrict__ Wm,    const float* __restrict__ Wih_m,
    const float* __restrict__ w_e,
    const float* __restrict__ fc_w,  const float* __restrict__ fc_b,
    float* __restrict__ h_m, float* __restrict__ wm, float* __restrict__ a_buf,
    int* __restrict__ bar, float* __restrict__ out)
{
    __shared__ __align__(16) float smem[(64 + 24) * 132];   // 46.5 KB
    float* Sh   = smem;               // [64][132]  activation tile (P1/P3)
    float* Wsh  = smem + 64 * 132;    // [24][132]  weight tile    (P1/P3)
    float* base = smem;               // [512]      (P2 alias)
    float* wesh = smem + 512;         // [512]      (P2 alias)
    float* sc   = smem + 1024;        // [64]       (P2 alias)

    const int w    = blockIdx.x;
    const int tid  = threadIdx.x;
    const int wv   = tid >> 6;
    const int lane = tid & 63;
    const int b0   = (w & 1) * 64;        // P1/P3: which half of the batch
    const int j0   = (w >> 1) * 8;        // P1/P3: 8-column slice
    int bcount = 0;

    // zero wm so step 0 (h_m = 0 -> wm = 0) needs no P1
    for (int i = tid; i < 512; i += 256) wm[w * 512 + i] = 0.0f;
    gsync(bar, (++bcount) * 128);

    for (int k = 0; k < 64; ++k) {
        // -------- P1 --------
        if (k > 0) {
            float acc0 = 0.f, acc1 = 0.f;
            for (int kc = 0; kc < 4; ++kc) {
                const int k0 = kc * 128;
                for (int v = tid; v < 2048; v += 256) {
                    int row = v >> 5, cq = v & 31;
                    *(float4*)&Sh[row * 132 + cq * 4] =
                        *(const float4*)&h_m[(b0 + row) * 512 + k0 + cq * 4];
                }
                {
                    int row = tid >> 5, cq = tid & 31;
                    *(float4*)&Wsh[row * 132 + cq * 4] =
                        *(const float4*)&Wm[(j0 + row) * 512 + k0 + cq * 4];
                }
                __syncthreads();
                const float* sr = &Sh[lane * 132];
                const float* w0 = &Wsh[(wv * 2 + 0) * 132];
                const float* w1 = &Wsh[(wv * 2 + 1) * 132];
#pragma unroll
                for (int cq = 0; cq < 32; ++cq) {
                    float4 s = *(const float4*)&sr[cq * 4];
                    float4 a = *(const float4*)&w0[cq * 4];
                    float4 b = *(const float4*)&w1[cq * 4];
                    acc0 += s.x * a.x + s.y * a.y + s.z * a.z + s.w * a.w;
                    acc1 += s.x * b.x + s.y * b.y + s.z * b.z + s.w * b.w;
                }
                __syncthreads();
            }
            wm[(b0 + lane) * 512 + j0 + wv * 2 + 0] = acc0;
            wm[(b0 + lane) * 512 + j0 + wv * 2 + 1] = acc1;
        }
        gsync(bar, (++bcount) * 128);

        // -------- P2: attention for b = w --------
        {
            const int b = w;
#pragma unroll
            for (int r = 0; r < 2; ++r) {
                int h = tid + r * 256;
                base[h] = pre_t[((size_t)k * 128 + b) * 512 + h] + wm[b * 512 + h];
                wesh[h] = w_e[h];
            }
            __syncthreads();
            for (int tt = 0; tt < 16; ++tt) {
                int t = wv * 16 + tt;
                const float* ps = pre_s + ((size_t)t * 128 + b) * 512;
                float p = 0.0f;
#pragma unroll
                for (int u = 0; u < 8; ++u) {
                    int h = lane + 64 * u;
                    p += wesh[h] * fast_tanh(ps[h] + base[h]);
                }
#pragma unroll
                for (int off = 32; off; off >>= 1) p += __shfl_xor(p, off);
                if (lane == 0) sc[t] = p;
            }
            __syncthreads();
            if (wv == 0) {
                float s = sc[lane];
                float mx = s;
#pragma unroll
                for (int off = 32; off; off >>= 1) mx = fmaxf(mx, __shfl_xor(mx, off));
                float e = __expf(s - mx);
                float sum = e;
#pragma unroll
                for (int off = 32; off; off >>= 1) sum += __shfl_xor(sum, off);
                sc[lane] = e / sum;
            }
            __syncthreads();
#pragma unroll
            for (int r = 0; r < 2; ++r) {
                int h = tid + r * 256;
                float acc = 0.0f;
                for (int t = 0; t < 64; ++t)
                    acc += sc[t] * h_s[((size_t)t * 128 + b) * 512 + h];
                a_buf[b * 512 + h] = acc;
            }
        }
        gsync(bar, (++bcount) * 128);

        // -------- P3 --------
        {
            float acc[2][3] = {};
            for (int kc = 0; kc < 4; ++kc) {
                const int k0 = kc * 128;
                for (int v = tid; v < 2048; v += 256) {
                    int row = v >> 5, cq = v & 31;
                    *(float4*)&Sh[row * 132 + cq * 4] =
                        *(const float4*)&a_buf[(b0 + row) * 512 + k0 + cq * 4];
                }
                for (int v = tid; v < 768; v += 256) {
                    int row = v >> 5, cq = v & 31;       // row in [0,24)
                    int g = row >> 3, j = row & 7;
                    int wrow = (g == 0 ? 0 : (g == 1 ? 1024 : 1536)) + j0 + j;
                    *(float4*)&Wsh[row * 132 + cq * 4] =
                        *(const float4*)&Wih_m[(size_t)wrow * 1024 + k0 + cq * 4];
                }
                __syncthreads();
                const float* sr = &Sh[lane * 132];
#pragma unroll
                for (int cq = 0; cq < 32; ++cq) {
                    float4 s = *(const float4*)&sr[cq * 4];
#pragma unroll
                    for (int jj = 0; jj < 2; ++jj)
#pragma unroll
                        for (int g = 0; g < 3; ++g) {
                            float4 ww = *(const float4*)&Wsh[(g * 8 + wv * 2 + jj) * 132 + cq * 4];
                            acc[jj][g] += s.x * ww.x + s.y * ww.y + s.z * ww.z + s.w * ww.w;
                        }
                }
                __syncthreads();
            }
            const size_t m = (size_t)k * 128 + b0 + lane;
#pragma unroll
            for (int jj = 0; jj < 2; ++jj) {
                int j = j0 + wv * 2 + jj;
                float gi = acc[jj][0] + pre_m_h[(m * 3 + 0) * 512 + j];
                float gg = acc[jj][1] + pre_m_h[(m * 3 + 1) * 512 + j];
                float go = acc[jj][2] + pre_m_h[(m * 3 + 2) * 512 + j];
                float c  = fast_sigmoid(gi) * fast_tanh(gg);
                h_m[(b0 + lane) * 512 + j] = fast_sigmoid(go) * fast_tanh(c);
            }
        }
        gsync(bar, (++bcount) * 128);
    }

    // -------- FC epilogue --------
    if (w < 96) {
        int idx = w * 4 + wv;                 // 0..383
        int b = idx / 3, c = idx % 3;
        float p = 0.0f;
#pragma unroll
        for (int u = 0; u < 8; ++u) {
            int h = lane + 64 * u;
            p += h_m[b * 512 + h] * fc_w[c * 512 + h];
        }
#pragma unroll
        for (int off = 32; off; off >>= 1) p += __shfl_xor(p, off);
        if (lane == 0) out[b * 3 + c] = p + fc_b[c];
    }
}

__global__ void zero_kernel(float* __restrict__ p, int n)
{
    int i = blockIdx.x * 256 + threadIdx.x;
    if (i < n) p[i] = 0.0f;
}

extern "C" void kernel_launch(void* const* d_in, const int* in_sizes, int n_in,
                              void* d_out, int out_size, void* d_ws, size_t ws_size,
                              hipStream_t stream)
{
    (void)in_sizes; (void)n_in; (void)out_size;
    const int*   premise    = (const int*)d_in[0];
    const int*   hypothesis = (const int*)d_in[2];
    const float* embed  = (const float*)d_in[4];
    const float* w_e    = (const float*)d_in[5];
    const float* Ws     = (const float*)d_in[6];
    const float* Wt     = (const float*)d_in[7];
    const float* Wm     = (const float*)d_in[8];
    const float* Wih_p  = (const float*)d_in[9];
    const float* bih_p  = (const float*)d_in[10];
    const float* bhh_p  = (const float*)d_in[11];
    const float* Wih_h  = (const float*)d_in[12];
    const float* bih_h  = (const float*)d_in[13];
    const float* bhh_h  = (const float*)d_in[14];
    const float* Wih_m  = (const float*)d_in[15];
    const float* bih_m  = (const float*)d_in[16];
    const float* bhh_m  = (const float*)d_in[17];
    const float* fc_w   = (const float*)d_in[18];
    const float* fc_b   = (const float*)d_in[19];

    float* ws      = (float*)d_ws;
    float* h_s     = ws;                      // 8192*512
    float* h_t     = h_s    + 4194304;
    float* pre_s   = h_t    + 4194304;
    float* pre_t   = pre_s  + 4194304;
    float* pre_m_h = pre_t  + 4194304;        // 8192*3*512
    float* h_m     = pre_m_h + 12582912;      // 128*512
    float* wm      = h_m    + 65536;
    float* a_buf   = wm     + 65536;
    int*   bar     = (int*)(a_buf + 65536);   // 64-int barrier slot
    float* outp    = (float*)d_out;
    if (ws_size < (size_t)(29556736 + 64) * 4) return;

    dim3 blk(256);

    // zero the barrier counter (d_ws is 0xAA-poisoned before every launch)
    zero_kernel<<<1, blk, 0, stream>>>((float*)bar, 64);

    // Phase A (parallel)
    gemm3_kernel<64, 3, 0, 1><<<dim3(128, 16), blk, 0, stream>>>(
        embed, premise, 300, Wih_p, 300, 300, bih_p, bhh_p, nullptr, h_s);
    gemm3_kernel<64, 3, 0, 1><<<dim3(128, 16), blk, 0, stream>>>(
        embed, hypothesis, 300, Wih_h, 300, 300, bih_h, bhh_h, nullptr, h_t);
    gemm3_kernel<64, 1, 3, 0><<<dim3(128, 16), blk, 0, stream>>>(
        h_s, nullptr, 512, Ws, 512, 512, nullptr, nullptr, nullptr, pre_s);
    gemm3_kernel<64, 1, 3, 0><<<dim3(128, 16), blk, 0, stream>>>(
        h_t, nullptr, 512, Wt, 512, 512, nullptr, nullptr, nullptr, pre_t);
    gemm3_kernel<64, 3, 1, 0><<<dim3(128, 16), blk, 0, stream>>>(
        h_t, nullptr, 512, Wih_m + 512, 1024, 512, bih_m, bhh_m, nullptr, pre_m_h);

    // Phase B (sequential, one persistent dispatch, manual grid barrier)
    phaseB_kernel<<<dim3(128), blk, 0, stream>>>(
        pre_s, pre_t, h_s, pre_m_h, Wm, Wih_m, w_e, fc_w, fc_b,
        h_m, wm, a_buf, bar, outp);
}